// Round 1
// baseline (590.106 us; speedup 1.0000x reference)
//
#include <hip/hip_runtime.h>
#include <math.h>

#define S     2048
#define D     1024
#define NMEM  32
#define KP    32     // PATCH_SIZE

// ---------- helpers ----------
__device__ inline double wave_red_sum(double v) {
    #pragma unroll
    for (int off = 32; off > 0; off >>= 1)
        v += __shfl_xor(v, off, 64);
    return v;
}

// ---------- K1: per-memory row entropy (fp64 accum) + column sums (fused) ----------
// grid: NMEM * (S/64) blocks, 256 threads. 4 waves x 16 rows each.
__global__ __launch_bounds__(256)
void k_entropy_colsum(const float* __restrict__ mem, float* __restrict__ entropy,
                      float* __restrict__ colsum) {
    const int tid  = threadIdx.x;
    const int wave = tid >> 6, lane = tid & 63;
    const int tiles = S / 64;
    const int n    = blockIdx.x / tiles;
    const int tile = blockIdx.x % tiles;
    const int s0   = tile * 64 + wave * 16;

    float colacc[16];
    #pragma unroll
    for (int i = 0; i < 16; ++i) colacc[i] = 0.f;

    const size_t base = (size_t)n * S * D;
    for (int r = 0; r < 16; ++r) {
        const int s = s0 + r;
        const float4* row = (const float4*)(mem + base + (size_t)s * D);
        double sm = 0.0, sq = 0.0;
        #pragma unroll
        for (int it = 0; it < 4; ++it) {
            float4 v = row[it * 64 + lane];
            sm += (double)v.x + (double)v.y + (double)v.z + (double)v.w;
            sq += (double)v.x * v.x + (double)v.y * v.y
                + (double)v.z * v.z + (double)v.w * v.w;
            colacc[it*4+0] += v.x; colacc[it*4+1] += v.y;
            colacc[it*4+2] += v.z; colacc[it*4+3] += v.w;
        }
        sm = wave_red_sum(sm);
        sq = wave_red_sum(sq);
        if (lane == 0) {
            double var = (sq - sm * sm / (double)D) / (double)(D - 1);
            entropy[n * S + s] = (float)sqrt(var > 0.0 ? var : 0.0);
        }
    }

    __shared__ float ldscol[D];
    for (int i = tid; i < D; i += 256) ldscol[i] = 0.f;
    __syncthreads();
    #pragma unroll
    for (int it = 0; it < 4; ++it) {
        #pragma unroll
        for (int j = 0; j < 4; ++j)
            atomicAdd(&ldscol[it*256 + lane*4 + j], colacc[it*4+j]);
    }
    __syncthreads();
    for (int i = tid; i < D; i += 256)
        atomicAdd(&colsum[n * D + i], ldscol[i]);
}

// ---------- query column sums ----------
// grid (D/256, S/32), 256 threads
__global__ __launch_bounds__(256)
void k_qcolsum(const float* __restrict__ q, float* __restrict__ qcol) {
    const int d  = blockIdx.x * 256 + threadIdx.x;
    const int s0 = blockIdx.y * 32;
    float acc = 0.f;
    #pragma unroll 4
    for (int r = 0; r < 32; ++r) acc += q[(size_t)(s0 + r) * D + d];
    atomicAdd(&qcol[d], acc);
}

// ---------- top-k (k=32) per problem; stable (lower index wins ties) ----------
__global__ __launch_bounds__(256)
void k_topk(const float* __restrict__ vals, int stride,
            int* __restrict__ outIdx, int outStride) {
    const int p = blockIdx.x;
    const float* v = vals + (size_t)p * stride;
    int* o = outIdx + (size_t)p * outStride;
    __shared__ float sv[S];
    __shared__ float rv[256];
    __shared__ int   ri[256];
    const int tid = threadIdx.x;
    for (int i = tid; i < S; i += 256) sv[i] = v[i];
    __syncthreads();
    for (int it = 0; it < KP; ++it) {
        float bv = -INFINITY; int bi = 0x7fffffff;
        for (int i = tid; i < S; i += 256) {
            float x = sv[i];
            if (x > bv) { bv = x; bi = i; }   // ascending scan keeps lowest idx on tie
        }
        rv[tid] = bv; ri[tid] = bi;
        __syncthreads();
        for (int off = 128; off > 0; off >>= 1) {
            if (tid < off) {
                float ov = rv[tid + off]; int oi = ri[tid + off];
                if (ov > rv[tid] || (ov == rv[tid] && oi < ri[tid])) {
                    rv[tid] = ov; ri[tid] = oi;
                }
            }
            __syncthreads();
        }
        if (tid == 0) { o[it] = ri[0]; sv[ri[0]] = -INFINITY; }
        __syncthreads();
    }
}

// ---------- aggregate init: agg = query / 33 ----------
__global__ __launch_bounds__(256)
void k_agg_init(const float* __restrict__ q, float* __restrict__ agg) {
    const size_t i = (size_t)blockIdx.x * 256 + threadIdx.x;
    const float c = 1.f / 33.f;
    float4 v = ((const float4*)q)[i];
    v.x *= c; v.y *= c; v.z *= c; v.w *= c;
    ((float4*)agg)[i] = v;
}

// ---------- scatter-add trunc(clip(mem rows))/33 into agg ----------
// grid NMEM*KP blocks, 256 threads (4 floats each)
__global__ __launch_bounds__(256)
void k_agg_scatter(const float* __restrict__ mem, const int* __restrict__ idx,
                   float* __restrict__ agg) {
    const int n = blockIdx.x / KP, j = blockIdx.x % KP;
    const int s = idx[n * KP + j];
    const size_t rb = ((size_t)n * S + s) * D;
    const float c = 1.f / 33.f;
    const int d = threadIdx.x * 4;
    float4 v = *(const float4*)(mem + rb + d);
    float t;
    t = truncf(fminf(fmaxf(v.x, -128.f), 127.f)); if (t != 0.f) atomicAdd(&agg[(size_t)s*D + d+0], t*c);
    t = truncf(fminf(fmaxf(v.y, -128.f), 127.f)); if (t != 0.f) atomicAdd(&agg[(size_t)s*D + d+1], t*c);
    t = truncf(fminf(fmaxf(v.z, -128.f), 127.f)); if (t != 0.f) atomicAdd(&agg[(size_t)s*D + d+2], t*c);
    t = truncf(fminf(fmaxf(v.w, -128.f), 127.f)); if (t != 0.f) atomicAdd(&agg[(size_t)s*D + d+3], t*c);
}

// ---------- row entropy of a [S,D] matrix (one block per row) ----------
__global__ __launch_bounds__(256)
void k_row_entropy(const float* __restrict__ a, float* __restrict__ ent) {
    const int s = blockIdx.x;
    const int tid = threadIdx.x, wave = tid >> 6, lane = tid & 63;
    float4 v = ((const float4*)(a + (size_t)s * D))[tid];
    double sm = (double)v.x + (double)v.y + (double)v.z + (double)v.w;
    double sq = (double)v.x * v.x + (double)v.y * v.y
              + (double)v.z * v.z + (double)v.w * v.w;
    sm = wave_red_sum(sm);
    sq = wave_red_sum(sq);
    __shared__ double wsm[4], wsq[4];
    if (lane == 0) { wsm[wave] = sm; wsq[wave] = sq; }
    __syncthreads();
    if (tid == 0) {
        double Sm = 0, Qq = 0;
        #pragma unroll
        for (int w = 0; w < 4; ++w) { Sm += wsm[w]; Qq += wsq[w]; }
        double var = (Qq - Sm * Sm / (double)D) / (double)(D - 1);
        ent[s] = (float)sqrt(var > 0.0 ? var : 0.0);
    }
}

// ---------- save trunc(clip(agg[row])) for selected rows ----------
__global__ __launch_bounds__(256)
void k_save_patch(const float* __restrict__ agg, const int* __restrict__ oidx,
                  float* __restrict__ patch) {
    const int j = blockIdx.x;
    const int s = oidx[j];
    const int d = threadIdx.x * 4;
    float4 v = *(const float4*)(agg + (size_t)s * D + d);
    float4 t;
    t.x = truncf(fminf(fmaxf(v.x, -128.f), 127.f));
    t.y = truncf(fminf(fmaxf(v.y, -128.f), 127.f));
    t.z = truncf(fminf(fmaxf(v.z, -128.f), 127.f));
    t.w = truncf(fminf(fmaxf(v.w, -128.f), 127.f));
    *(float4*)(patch + (size_t)j * D + d) = t;
}

__global__ __launch_bounds__(256)
void k_zero(float* __restrict__ p) {
    const size_t i = (size_t)blockIdx.x * 256 + threadIdx.x;
    ((float4*)p)[i] = make_float4(0.f, 0.f, 0.f, 0.f);
}

__global__ __launch_bounds__(256)
void k_write_patch(const float* __restrict__ patch, const int* __restrict__ oidx,
                   float* __restrict__ recon) {
    const int j = blockIdx.x;
    const int s = oidx[j];
    const int d = threadIdx.x * 4;
    *(float4*)(recon + (size_t)s * D + d) = *(const float4*)(patch + (size_t)j * D + d);
}

// ---------- MLP layer 1: hidden[m][h] = relu(b1 + feats @ W1) ----------
// grid NMEM+1 blocks (block 32 == query), 128 threads
__global__ __launch_bounds__(128)
void k_mlp1(const float* __restrict__ colsum, const float* __restrict__ qcol,
            const float* __restrict__ surprise,
            const float* __restrict__ W1, const float* __restrict__ b1,
            float* __restrict__ hidden) {
    const int m = blockIdx.x;
    const int h = threadIdx.x;
    __shared__ float lf[D];
    const float inv = 1.f / (float)S;
    const float* src = (m < NMEM) ? (colsum + (size_t)m * D) : qcol;
    for (int i = h; i < D; i += 128) lf[i] = src[i] * inv;
    __syncthreads();
    float acc = b1[h];
    #pragma unroll 8
    for (int j = 0; j < D; ++j) acc += lf[j] * W1[(size_t)j * 128 + h];
    const float sur = (m < NMEM) ? surprise[m] : 0.f;
    acc += sur * W1[(size_t)D * 128 + h];          // feat j=1024; j=1025/1026 are zeros
    hidden[(size_t)m * 128 + h] = fmaxf(acc, 0.f);
}

// ---------- MLP layer 2: emb[m][d] = b2 + hidden @ W2 ----------
// grid (NMEM+1, D/256), 256 threads
__global__ __launch_bounds__(256)
void k_mlp2(const float* __restrict__ hidden, const float* __restrict__ W2,
            const float* __restrict__ b2, float* __restrict__ emb) {
    const int m = blockIdx.x;
    const int d = blockIdx.y * 256 + threadIdx.x;
    __shared__ float lh[128];
    if (threadIdx.x < 128) lh[threadIdx.x] = hidden[(size_t)m * 128 + threadIdx.x];
    __syncthreads();
    float acc = b2[d];
    #pragma unroll 8
    for (int k = 0; k < 128; ++k) acc += lh[k] * W2[(size_t)k * D + d];
    emb[(size_t)m * D + d] = acc;
}

// ---------- per-row ||emb||^2 and dot with q_emb ----------
__global__ __launch_bounds__(256)
void k_simsdot(const float* __restrict__ emb, float* __restrict__ ssq,
               float* __restrict__ dotv) {
    const int m = blockIdx.x;
    const int tid = threadIdx.x, wave = tid >> 6, lane = tid & 63;
    float4 v = ((const float4*)(emb + (size_t)m * D))[tid];
    float4 q = ((const float4*)(emb + (size_t)NMEM * D))[tid];
    double ss = (double)v.x * v.x + (double)v.y * v.y
              + (double)v.z * v.z + (double)v.w * v.w;
    double dt = (double)v.x * q.x + (double)v.y * q.y
              + (double)v.z * q.z + (double)v.w * q.w;
    ss = wave_red_sum(ss);
    dt = wave_red_sum(dt);
    __shared__ double wss[4], wdt[4];
    if (lane == 0) { wss[wave] = ss; wdt[wave] = dt; }
    __syncthreads();
    if (tid == 0) {
        double a = 0, b = 0;
        #pragma unroll
        for (int w = 0; w < 4; ++w) { a += wss[w]; b += wdt[w]; }
        ssq[m] = (float)a;
        if (m < NMEM) dotv[m] = (float)b;
    }
}

// ---------- final: sims, stable descending rank -> top_idx ----------
__global__ __launch_bounds__(64)
void k_final(const float* __restrict__ ssq, const float* __restrict__ dotv,
             const float* __restrict__ prio, float* __restrict__ outSims,
             float* __restrict__ outIdx) {
    __shared__ float sims[NMEM];
    const int t = threadIdx.x;
    const float qn = fmaxf(sqrtf(ssq[NMEM]), 1e-8f);
    if (t < NMEM) {
        const float mn = fmaxf(sqrtf(ssq[t]), 1e-8f);
        const float sv = dotv[t] / (mn * qn) * prio[t];
        sims[t] = sv;
        outSims[t] = sv;
    }
    __syncthreads();
    if (t < NMEM) {
        const float si = sims[t];
        int rank = 0;
        #pragma unroll
        for (int j = 0; j < NMEM; ++j) {
            const float sj = sims[j];
            if (sj > si || (sj == si && j < t)) ++rank;
        }
        outIdx[rank] = (float)t;
    }
}

extern "C" void kernel_launch(void* const* d_in, const int* in_sizes, int n_in,
                              void* d_out, int out_size, void* d_ws, size_t ws_size,
                              hipStream_t stream) {
    const float* query    = (const float*)d_in[0];
    const float* memories = (const float*)d_in[1];
    const float* surprise = (const float*)d_in[2];
    const float* priority = (const float*)d_in[3];
    const float* W1 = (const float*)d_in[4];
    const float* b1 = (const float*)d_in[5];
    const float* W2 = (const float*)d_in[6];
    const float* b2 = (const float*)d_in[7];
    float* out = (float*)d_out;
    char*  ws  = (char*)d_ws;

    // ws layout (bytes)
    float* colsum  = (float*)(ws + 0);        // 131072
    float* qcol    = (float*)(ws + 131072);   // 4096   (memset [0,135168))
    float* entropy = (float*)(ws + 135168);   // 262144
    int*   idxMem  = (int*)  (ws + 397312);   // 4096
    float* entAgg  = (float*)(ws + 401408);   // 8192
    int*   outIdxI = (int*)  (ws + 409600);   // 256
    float* hidden  = (float*)(ws + 409856);   // 16896
    float* emb     = (float*)(ws + 426752);   // 135168
    float* ssq     = (float*)(ws + 561920);   // 256
    float* dotv    = (float*)(ws + 562176);   // 256
    float* patch   = (float*)(ws + 562432);   // 131072 -> end 693504

    float* agg       = out;                   // reuse recon region as aggregate scratch
    float* outSims   = out + (size_t)S * D;
    float* outTopIdx = outSims + NMEM;

    hipMemsetAsync(ws, 0, 135168, stream);    // colsum + qcol atomic targets

    k_entropy_colsum<<<NMEM * (S / 64), 256, 0, stream>>>(memories, entropy, colsum);
    k_qcolsum<<<dim3(D / 256, S / 32), 256, 0, stream>>>(query, qcol);
    k_topk<<<NMEM, 256, 0, stream>>>(entropy, S, idxMem, KP);
    k_agg_init<<<(S * D) / 1024, 256, 0, stream>>>(query, agg);
    k_agg_scatter<<<NMEM * KP, 256, 0, stream>>>(memories, idxMem, agg);
    k_row_entropy<<<S, 256, 0, stream>>>(agg, entAgg);
    k_topk<<<1, 256, 0, stream>>>(entAgg, S, outIdxI, KP);
    k_save_patch<<<KP, 256, 0, stream>>>(agg, outIdxI, patch);
    k_zero<<<(S * D) / 1024, 256, 0, stream>>>(out);
    k_write_patch<<<KP, 256, 0, stream>>>(patch, outIdxI, out);
    k_mlp1<<<NMEM + 1, 128, 0, stream>>>(colsum, qcol, surprise, W1, b1, hidden);
    k_mlp2<<<dim3(NMEM + 1, D / 256), 256, 0, stream>>>(hidden, W2, b2, emb);
    k_simsdot<<<NMEM + 1, 256, 0, stream>>>(emb, ssq, dotv);
    k_final<<<1, 64, 0, stream>>>(ssq, dotv, priority, outSims, outTopIdx);
}